// Round 6
// baseline (136.065 us; speedup 1.0000x reference)
//
#include <hip/hip_runtime.h>
#include <stdint.h>

#define NROWS (512*256)          // 131072
#define DDIM 128
#define KCB 1024
#define TOTALF (NROWS*DDIM)      // 16777216
#define TAU 0.35f                // refine gate vs 2nd-best gap
#define IDXMASK 0xFFFFFC00u      // clear low 10 mantissa bits for packed argmin keys

typedef __attribute__((ext_vector_type(8))) short short8v;
typedef __attribute__((ext_vector_type(4))) float f32x4;

static __device__ __forceinline__ unsigned short bf16_rne(float f) {
    unsigned u = __builtin_bit_cast(unsigned, f);
    u += 0x7FFFu + ((u >> 16) & 1u);
    return (unsigned short)(u >> 16);
}
static __device__ __forceinline__ float bf16_to_f32(unsigned short h) {
    unsigned u = ((unsigned)h) << 16;
    return __builtin_bit_cast(float, u);
}

// ---- prep: 64 blocks; block b -> chunk cidx=b>>2, col-group n=b&3 (16 cols).
// Outputs: ebT_f32[K][D], fragment-major bf16-hi blob, enorm. (unchanged from r5)
__global__ __launch_bounds__(256) void vq_prep(
    const float* __restrict__ emb,
    float* __restrict__ ebT_f32,
    char* __restrict__ ebfrag,
    float* __restrict__ enorm)
{
    __shared__ float T[128 * 17];
    __shared__ float red[256];
    const int t = threadIdx.x;
    const int cidx = blockIdx.x >> 2;
    const int n = blockIdx.x & 3;
    const int k0 = cidx * 64 + n * 16;
    {
        const int c16 = t & 15;
        const int dq = t >> 4;
        #pragma unroll
        for (int i = 0; i < 8; ++i) {
            int d = dq * 8 + i;
            T[d * 17 + c16] = emb[(size_t)d * KCB + k0 + c16];
        }
    }
    __syncthreads();
    {
        const int c16 = t & 15, part = t >> 4;
        float s = 0.f;
        #pragma unroll
        for (int i = 0; i < 8; ++i) { float v = T[(part*8+i)*17 + c16]; s = fmaf(v, v, s); }
        red[part * 16 + c16] = s;
    }
    {
        const int col = t >> 4;
        const int d0 = (t & 15) * 8;
        f32x4 w0, w1;
        #pragma unroll
        for (int j = 0; j < 4; ++j) w0[j] = T[(d0 + j) * 17 + col];
        #pragma unroll
        for (int j = 0; j < 4; ++j) w1[j] = T[(d0 + 4 + j) * 17 + col];
        *(f32x4*)(ebT_f32 + (size_t)(k0 + col) * DDIM + d0) = w0;
        *(f32x4*)(ebT_f32 + (size_t)(k0 + col) * DDIM + d0 + 4) = w1;
    }
    {
        const int s = t >> 6, l = t & 63;
        const int cc = l & 15, g = l >> 4;
        const int d0 = s * 32 + g * 8;
        short8v hv;
        #pragma unroll
        for (int j = 0; j < 8; ++j) hv[j] = (short)bf16_rne(T[(d0 + j) * 17 + cc]);
        *(short8v*)(ebfrag + (size_t)cidx * 16384 + (s * 4 + n) * 1024 + l * 16) = hv;
    }
    __syncthreads();
    if (t < 16) {
        float s = 0.f;
        #pragma unroll
        for (int p = 0; p < 16; ++p) s += red[p * 16 + t];
        enorm[k0 + t] = s;
    }
}

// ---- main: 32 rows/wave, 4 waves/SIMD. No LDS/barriers; packed top-3 argmin.
__global__ __launch_bounds__(256, 4) void vq_main(
    const float* __restrict__ x,
    const char* __restrict__ ebfrag,
    const float* __restrict__ ebT_f32,
    const float* __restrict__ enorm,
    float* __restrict__ out,
    float* __restrict__ loss_acc)
{
    const int tid = threadIdx.x, wid = tid >> 6, lane = tid & 63;
    const int c = lane & 15, g = lane >> 4;
    const size_t wave_row = ((size_t)blockIdx.x * 4 + wid) * 32;

    // A fragments: 32 rows x 128 d, split hi/lo (64 VGPR total)
    short8v a_hi[2][4], a_lo[2][4];
    float xsq = 0.f;
    #pragma unroll
    for (int m = 0; m < 2; ++m) {
      #pragma unroll
      for (int s = 0; s < 4; ++s) {
        const float* src = x + (wave_row + m * 16 + c) * DDIM + s * 32 + g * 8;
        f32x4 v0 = *(const f32x4*)src;
        f32x4 v1 = *(const f32x4*)(src + 4);
        #pragma unroll
        for (int j = 0; j < 8; ++j) {
            float f = (j < 4) ? v0[j] : v1[j - 4];
            unsigned short h = bf16_rne(f);
            float fh = bf16_to_f32(h);
            a_hi[m][s][j] = (short)h;
            a_lo[m][s][j] = (short)bf16_rne(f - fh);
            xsq = fmaf(f, f, xsq);
        }
      }
    }

    float tb[2][4], ts2[2][4], tt[2][4];
    #pragma unroll
    for (int m = 0; m < 2; ++m)
      #pragma unroll
      for (int r = 0; r < 4; ++r) { tb[m][r] = 3.4e38f; ts2[m][r] = 3.4e38f; tt[m][r] = 3.4e38f; }

    // flat 64-iteration loop (cidx = it>>2, n = it&3); colv = it*16 + c
    #pragma unroll 2
    for (int it = 0; it < 64; ++it) {
        const char* bb = ebfrag + (size_t)(it >> 2) * 16384 + (it & 3) * 1024 + lane * 16;
        short8v bh[4];
        #pragma unroll
        for (int s = 0; s < 4; ++s)
            bh[s] = *(const short8v*)(bb + s * 4096);
        const int colv = it * 16 + c;
        const float en = enorm[colv];
        f32x4 acc[2];
        #pragma unroll
        for (int m = 0; m < 2; ++m) acc[m] = (f32x4){0.f, 0.f, 0.f, 0.f};
        #pragma unroll
        for (int s = 0; s < 4; ++s) {
            #pragma unroll
            for (int m = 0; m < 2; ++m)
                acc[m] = __builtin_amdgcn_mfma_f32_16x16x32_bf16(a_hi[m][s], bh[s], acc[m], 0, 0, 0);
            #pragma unroll
            for (int m = 0; m < 2; ++m)
                acc[m] = __builtin_amdgcn_mfma_f32_16x16x32_bf16(a_lo[m][s], bh[s], acc[m], 0, 0, 0);
        }
        #pragma unroll
        for (int m = 0; m < 2; ++m)
          #pragma unroll
          for (int r = 0; r < 4; ++r) {
            float d = fmaf(-2.f, acc[m][r], en);          // ||x||^2 omitted
            unsigned db = __builtin_bit_cast(unsigned, d);
            float key = __builtin_bit_cast(float, (db & IDXMASK) | (unsigned)colv);
            tt[m][r]  = __builtin_amdgcn_fmed3f(key, ts2[m][r], tt[m][r]);  // new 3rd
            ts2[m][r] = __builtin_amdgcn_fmed3f(key, tb[m][r],  ts2[m][r]); // new 2nd
            tb[m][r]  = fminf(key, tb[m][r]);                                // new 1st
          }
    }

    // cross-lane top-3 merge over the 16 c-lanes (disjoint col sets)
    #pragma unroll
    for (int m = 0; m < 2; ++m)
      #pragma unroll
      for (int r = 0; r < 4; ++r) {
        float b = tb[m][r], s = ts2[m][r], t3 = tt[m][r];
        #pragma unroll
        for (int off = 1; off < 16; off <<= 1) {
            float ob = __shfl_xor(b, off, 64);
            float os = __shfl_xor(s, off, 64);
            float ot = __shfl_xor(t3, off, 64);
            t3 = __builtin_amdgcn_fmed3f(ob, s, t3);
            s  = __builtin_amdgcn_fmed3f(ob, b, s);
            b  = fminf(b, ob);
            t3 = __builtin_amdgcn_fmed3f(os, s, t3);
            s  = fminf(s, os);
            t3 = fminf(t3, ot);
        }
        tb[m][r] = b; ts2[m][r] = s; tt[m][r] = t3;
      }

    // refine: exact fp32 over top-3 where the 2nd-best gap is small
    float lsum = 0.f;
    #pragma unroll
    for (int m = 0; m < 2; ++m)
      #pragma unroll
      for (int r = 0; r < 4; ++r) {
        unsigned b1 = __builtin_bit_cast(unsigned, tb[m][r]);
        unsigned b2 = __builtin_bit_cast(unsigned, ts2[m][r]);
        int chosen = (int)(b1 & 1023u);
        float dch = __builtin_bit_cast(float, b1 & IDXMASK);
        float d2a = __builtin_bit_cast(float, b2 & IDXMASK);
        const size_t row = wave_row + m * 16 + g * 4 + r;
        if (d2a - dch < TAU) {      // uniform within 16-lane group
            unsigned b3 = __builtin_bit_cast(unsigned, tt[m][r]);
            int i1 = chosen, i2 = (int)(b2 & 1023u), i3 = (int)(b3 & 1023u);
            const f32x4* xp = (const f32x4*)(x + row * DDIM + c * 8);
            f32x4 x0 = xp[0], x1 = xp[1];
            const f32x4* e1 = (const f32x4*)(ebT_f32 + (size_t)i1 * DDIM + c * 8);
            const f32x4* e2 = (const f32x4*)(ebT_f32 + (size_t)i2 * DDIM + c * 8);
            const f32x4* e3 = (const f32x4*)(ebT_f32 + (size_t)i3 * DDIM + c * 8);
            f32x4 p10 = e1[0], p11 = e1[1];
            f32x4 p20 = e2[0], p21 = e2[1];
            f32x4 p30 = e3[0], p31 = e3[1];
            float q1 = 0.f, q2 = 0.f, q3 = 0.f;
            #pragma unroll
            for (int j = 0; j < 4; ++j) {
                q1 = fmaf(x0[j], p10[j], q1); q1 = fmaf(x1[j], p11[j], q1);
                q2 = fmaf(x0[j], p20[j], q2); q2 = fmaf(x1[j], p21[j], q2);
                q3 = fmaf(x0[j], p30[j], q3); q3 = fmaf(x1[j], p31[j], q3);
            }
            #pragma unroll
            for (int off = 1; off < 16; off <<= 1) {
                q1 += __shfl_xor(q1, off, 64);
                q2 += __shfl_xor(q2, off, 64);
                q3 += __shfl_xor(q3, off, 64);
            }
            float D1 = fmaf(-2.f, q1, enorm[i1]);
            float D2 = fmaf(-2.f, q2, enorm[i2]);
            float D3 = fmaf(-2.f, q3, enorm[i3]);
            float bd = D1; int bi = i1;
            if (D2 < bd || (D2 == bd && i2 < bi)) { bd = D2; bi = i2; }
            if (D3 < bd || (D3 == bd && i3 < bi)) { bd = D3; bi = i3; }
            chosen = bi; dch = bd;
        }
        const f32x4* qsrc = (const f32x4*)(ebT_f32 + (size_t)chosen * DDIM + c * 8);
        f32x4* dst = (f32x4*)(out + row * DDIM + c * 8);
        dst[0] = qsrc[0];
        dst[1] = qsrc[1];
        if (c == 0) lsum += dch;
      }

    // loss: sum(||x||^2) + sum(best_dist) == sum((q-x)^2)
    float part = xsq + lsum;
    #pragma unroll
    for (int off = 32; off > 0; off >>= 1) part += __shfl_down(part, off, 64);
    if (lane == 0) atomicAdd(loss_acc, part);
}

__global__ void vq_finalize(const float* __restrict__ loss_acc,
                            float* __restrict__ outl) {
    if (threadIdx.x == 0) {
        float l = loss_acc[0] * (1.0f / (float)TOTALF);
        outl[0] = l;           // codebook_loss
        outl[1] = 0.25f * l;   // commitment_loss = BETA * same value
    }
}

// ws layout: [0,512K) ebT_f32 | [512K,768K) ebfrag (fragment-major bf16-hi)
//            [768K,772K) enorm | [772K] loss_acc
extern "C" void kernel_launch(void* const* d_in, const int* in_sizes, int n_in,
                              void* d_out, int out_size, void* d_ws, size_t ws_size,
                              hipStream_t stream) {
    const float* x   = (const float*)d_in[0];
    const float* emb = (const float*)d_in[1];
    float* out = (float*)d_out;
    char* ws = (char*)d_ws;
    float* ebT_f32  = (float*)ws;
    char*  ebfrag   = ws + 512 * 1024;
    float* enormp   = (float*)(ws + 768 * 1024);
    float* loss_acc = (float*)(ws + 772 * 1024);

    hipMemsetAsync(loss_acc, 0, sizeof(float), stream);
    vq_prep<<<64, 256, 0, stream>>>(emb, ebT_f32, ebfrag, enormp);
    vq_main<<<NROWS / 128, 256, 0, stream>>>(x, ebfrag, ebT_f32, enormp, out, loss_acc);
    vq_finalize<<<1, 64, 0, stream>>>(loss_acc, out + (size_t)TOTALF);
}

// Round 8
// 120.189 us; speedup vs baseline: 1.1321x; 1.1321x over previous
//
#include <hip/hip_runtime.h>
#include <stdint.h>

#define NROWS (512*256)          // 131072
#define DDIM 128
#define KCB 1024
#define TOTALF (NROWS*DDIM)      // 16777216
#define TAU 0.35f                // refine gate vs 2nd-best gap (r5-proven)
#define IDXMASK 0xFFFFFC00u      // clear low 10 mantissa bits for packed argmin keys

typedef __attribute__((ext_vector_type(8))) short short8v;
typedef __attribute__((ext_vector_type(4))) float f32x4;

static __device__ __forceinline__ unsigned short bf16_rne(float f) {
    unsigned u = __builtin_bit_cast(unsigned, f);
    u += 0x7FFFu + ((u >> 16) & 1u);
    return (unsigned short)(u >> 16);
}
static __device__ __forceinline__ float bf16_to_f32(unsigned short h) {
    unsigned u = ((unsigned)h) << 16;
    return __builtin_bit_cast(float, u);
}

// ---- prep: 64 blocks; block b -> chunk cidx=b>>2, col-group n=b&3 (16 cols).
// Outputs: ebT_f32[K][D], fragment-major bf16-hi blob, enorm. (unchanged)
__global__ __launch_bounds__(256) void vq_prep(
    const float* __restrict__ emb,
    float* __restrict__ ebT_f32,
    char* __restrict__ ebfrag,
    float* __restrict__ enorm)
{
    __shared__ float T[128 * 17];
    __shared__ float red[256];
    const int t = threadIdx.x;
    const int cidx = blockIdx.x >> 2;
    const int n = blockIdx.x & 3;
    const int k0 = cidx * 64 + n * 16;
    {
        const int c16 = t & 15;
        const int dq = t >> 4;
        #pragma unroll
        for (int i = 0; i < 8; ++i) {
            int d = dq * 8 + i;
            T[d * 17 + c16] = emb[(size_t)d * KCB + k0 + c16];
        }
    }
    __syncthreads();
    {
        const int c16 = t & 15, part = t >> 4;
        float s = 0.f;
        #pragma unroll
        for (int i = 0; i < 8; ++i) { float v = T[(part*8+i)*17 + c16]; s = fmaf(v, v, s); }
        red[part * 16 + c16] = s;
    }
    {
        const int col = t >> 4;
        const int d0 = (t & 15) * 8;
        f32x4 w0, w1;
        #pragma unroll
        for (int j = 0; j < 4; ++j) w0[j] = T[(d0 + j) * 17 + col];
        #pragma unroll
        for (int j = 0; j < 4; ++j) w1[j] = T[(d0 + 4 + j) * 17 + col];
        *(f32x4*)(ebT_f32 + (size_t)(k0 + col) * DDIM + d0) = w0;
        *(f32x4*)(ebT_f32 + (size_t)(k0 + col) * DDIM + d0 + 4) = w1;
    }
    {
        const int s = t >> 6, l = t & 63;
        const int cc = l & 15, g = l >> 4;
        const int d0 = s * 32 + g * 8;
        short8v hv;
        #pragma unroll
        for (int j = 0; j < 8; ++j) hv[j] = (short)bf16_rne(T[(d0 + j) * 17 + cc]);
        *(short8v*)(ebfrag + (size_t)cidx * 16384 + (s * 4 + n) * 1024 + l * 16) = hv;
    }
    __syncthreads();
    if (t < 16) {
        float s = 0.f;
        #pragma unroll
        for (int p = 0; p < 16; ++p) s += red[p * 16 + t];
        enorm[k0 + t] = s;
    }
}

// ---- main: r5 logic (2-pass split-bf16, top-3, TAU=0.35) + explicit
//      1-iteration register prefetch of B-fragments and enorm.
__global__ __launch_bounds__(256, 2) void vq_main(
    const float* __restrict__ x,
    const char* __restrict__ ebfrag,
    const float* __restrict__ ebT_f32,
    const float* __restrict__ enorm,
    float* __restrict__ out,
    float* __restrict__ loss_acc)
{
    const int tid = threadIdx.x, wid = tid >> 6, lane = tid & 63;
    const int c = lane & 15, g = lane >> 4;
    const size_t wave_row = ((size_t)blockIdx.x * 4 + wid) * 64;

    // A fragments: 64 rows x 128 d, split hi/lo (layout r3/r5-proven)
    short8v a_hi[4][4], a_lo[4][4];
    float xsq = 0.f;
    #pragma unroll
    for (int m = 0; m < 4; ++m) {
      #pragma unroll
      for (int s = 0; s < 4; ++s) {
        const float* src = x + (wave_row + m * 16 + c) * DDIM + s * 32 + g * 8;
        f32x4 v0 = *(const f32x4*)src;
        f32x4 v1 = *(const f32x4*)(src + 4);
        #pragma unroll
        for (int j = 0; j < 8; ++j) {
            float f = (j < 4) ? v0[j] : v1[j - 4];
            unsigned short h = bf16_rne(f);
            float fh = bf16_to_f32(h);
            a_hi[m][s][j] = (short)h;
            a_lo[m][s][j] = (short)bf16_rne(f - fh);
            xsq = fmaf(f, f, xsq);
        }
      }
    }

    float tb[4][4], ts2[4][4], tt[4][4];
    #pragma unroll
    for (int m = 0; m < 4; ++m)
      #pragma unroll
      for (int r = 0; r < 4; ++r) { tb[m][r] = 3.4e38f; ts2[m][r] = 3.4e38f; tt[m][r] = 3.4e38f; }

    // ---- prologue: load it=0's B-fragments + enorm into registers
    short8v bh_cur[4];
    {
        const char* bb = ebfrag + lane * 16;          // it=0 -> cidx=0, n=0
        #pragma unroll
        for (int s = 0; s < 4; ++s)
            bh_cur[s] = *(const short8v*)(bb + s * 4096);
    }
    float en_cur = enorm[c];

    // flat 64-iteration loop; iter i prefetches i+1's B while computing i
    #pragma unroll 2
    for (int it = 0; it < 64; ++it) {
        const int itn = (it + 1) & 63;                 // 63 re-reads it=0 (L1-hot, discarded)
        const char* bbn = ebfrag + (size_t)(itn >> 2) * 16384 + (itn & 3) * 1024 + lane * 16;
        short8v bh_nxt[4];
        #pragma unroll
        for (int s = 0; s < 4; ++s)
            bh_nxt[s] = *(const short8v*)(bbn + s * 4096);
        float en_nxt = enorm[itn * 16 + c];

        const int colv = it * 16 + c;
        f32x4 acc[4];
        #pragma unroll
        for (int m = 0; m < 4; ++m) acc[m] = (f32x4){0.f, 0.f, 0.f, 0.f};
        #pragma unroll
        for (int s = 0; s < 4; ++s) {
            #pragma unroll
            for (int m = 0; m < 4; ++m)
                acc[m] = __builtin_amdgcn_mfma_f32_16x16x32_bf16(a_hi[m][s], bh_cur[s], acc[m], 0, 0, 0);
            #pragma unroll
            for (int m = 0; m < 4; ++m)
                acc[m] = __builtin_amdgcn_mfma_f32_16x16x32_bf16(a_lo[m][s], bh_cur[s], acc[m], 0, 0, 0);
        }
        #pragma unroll
        for (int m = 0; m < 4; ++m)
          #pragma unroll
          for (int r = 0; r < 4; ++r) {
            float d = fmaf(-2.f, acc[m][r], en_cur);      // ||x||^2 omitted
            unsigned db = __builtin_bit_cast(unsigned, d);
            float key = __builtin_bit_cast(float, (db & IDXMASK) | (unsigned)colv);
            tt[m][r]  = __builtin_amdgcn_fmed3f(key, ts2[m][r], tt[m][r]);  // new 3rd
            ts2[m][r] = __builtin_amdgcn_fmed3f(key, tb[m][r],  ts2[m][r]); // new 2nd
            tb[m][r]  = fminf(key, tb[m][r]);                                // new 1st
          }
        #pragma unroll
        for (int s = 0; s < 4; ++s) bh_cur[s] = bh_nxt[s];
        en_cur = en_nxt;
    }

    // cross-lane top-3 merge over the 16 c-lanes (disjoint col sets)
    #pragma unroll
    for (int m = 0; m < 4; ++m)
      #pragma unroll
      for (int r = 0; r < 4; ++r) {
        float b = tb[m][r], s = ts2[m][r], t3 = tt[m][r];
        #pragma unroll
        for (int off = 1; off < 16; off <<= 1) {
            float ob = __shfl_xor(b, off, 64);
            float os = __shfl_xor(s, off, 64);
            float ot = __shfl_xor(t3, off, 64);
            t3 = __builtin_amdgcn_fmed3f(ob, s, t3);
            s  = __builtin_amdgcn_fmed3f(ob, b, s);
            b  = fminf(b, ob);
            t3 = __builtin_amdgcn_fmed3f(os, s, t3);
            s  = fminf(s, os);
            t3 = fminf(t3, ot);
        }
        tb[m][r] = b; ts2[m][r] = s; tt[m][r] = t3;
      }

    // refine: exact fp32 over top-3 where the 2nd-best gap is small
    float lsum = 0.f;
    #pragma unroll
    for (int m = 0; m < 4; ++m)
      #pragma unroll
      for (int r = 0; r < 4; ++r) {
        unsigned b1 = __builtin_bit_cast(unsigned, tb[m][r]);
        unsigned b2 = __builtin_bit_cast(unsigned, ts2[m][r]);
        int chosen = (int)(b1 & 1023u);
        float dch = __builtin_bit_cast(float, b1 & IDXMASK);
        float d2a = __builtin_bit_cast(float, b2 & IDXMASK);
        const size_t row = wave_row + m * 16 + g * 4 + r;
        if (d2a - dch < TAU) {      // uniform within 16-lane group
            unsigned b3 = __builtin_bit_cast(unsigned, tt[m][r]);
            int i1 = chosen, i2 = (int)(b2 & 1023u), i3 = (int)(b3 & 1023u);
            const f32x4* xp = (const f32x4*)(x + row * DDIM + c * 8);
            f32x4 x0 = xp[0], x1 = xp[1];
            const f32x4* e1 = (const f32x4*)(ebT_f32 + (size_t)i1 * DDIM + c * 8);
            const f32x4* e2 = (const f32x4*)(ebT_f32 + (size_t)i2 * DDIM + c * 8);
            const f32x4* e3 = (const f32x4*)(ebT_f32 + (size_t)i3 * DDIM + c * 8);
            f32x4 p10 = e1[0], p11 = e1[1];
            f32x4 p20 = e2[0], p21 = e2[1];
            f32x4 p30 = e3[0], p31 = e3[1];
            float q1 = 0.f, q2 = 0.f, q3 = 0.f;
            #pragma unroll
            for (int j = 0; j < 4; ++j) {
                q1 = fmaf(x0[j], p10[j], q1); q1 = fmaf(x1[j], p11[j], q1);
                q2 = fmaf(x0[j], p20[j], q2); q2 = fmaf(x1[j], p21[j], q2);
                q3 = fmaf(x0[j], p30[j], q3); q3 = fmaf(x1[j], p31[j], q3);
            }
            #pragma unroll
            for (int off = 1; off < 16; off <<= 1) {
                q1 += __shfl_xor(q1, off, 64);
                q2 += __shfl_xor(q2, off, 64);
                q3 += __shfl_xor(q3, off, 64);
            }
            float D1 = fmaf(-2.f, q1, enorm[i1]);
            float D2 = fmaf(-2.f, q2, enorm[i2]);
            float D3 = fmaf(-2.f, q3, enorm[i3]);
            float bd = D1; int bi = i1;
            if (D2 < bd || (D2 == bd && i2 < bi)) { bd = D2; bi = i2; }
            if (D3 < bd || (D3 == bd && i3 < bi)) { bd = D3; bi = i3; }
            chosen = bi; dch = bd;
        }
        const f32x4* qsrc = (const f32x4*)(ebT_f32 + (size_t)chosen * DDIM + c * 8);
        f32x4* dst = (f32x4*)(out + row * DDIM + c * 8);
        dst[0] = qsrc[0];
        dst[1] = qsrc[1];
        if (c == 0) lsum += dch;
      }

    // loss: sum(||x||^2) + sum(best_dist) == sum((q-x)^2)
    float part = xsq + lsum;
    #pragma unroll
    for (int off = 32; off > 0; off >>= 1) part += __shfl_down(part, off, 64);
    if (lane == 0) atomicAdd(loss_acc, part);
}

__global__ void vq_finalize(const float* __restrict__ loss_acc,
                            float* __restrict__ outl) {
    if (threadIdx.x == 0) {
        float l = loss_acc[0] * (1.0f / (float)TOTALF);
        outl[0] = l;           // codebook_loss
        outl[1] = 0.25f * l;   // commitment_loss = BETA * same value
    }
}

// ws layout: [0,512K) ebT_f32 | [512K,768K) ebfrag (fragment-major bf16-hi)
//            [768K,772K) enorm | [772K] loss_acc
extern "C" void kernel_launch(void* const* d_in, const int* in_sizes, int n_in,
                              void* d_out, int out_size, void* d_ws, size_t ws_size,
                              hipStream_t stream) {
    const float* x   = (const float*)d_in[0];
    const float* emb = (const float*)d_in[1];
    float* out = (float*)d_out;
    char* ws = (char*)d_ws;
    float* ebT_f32  = (float*)ws;
    char*  ebfrag   = ws + 512 * 1024;
    float* enormp   = (float*)(ws + 768 * 1024);
    float* loss_acc = (float*)(ws + 772 * 1024);

    hipMemsetAsync(loss_acc, 0, sizeof(float), stream);
    vq_prep<<<64, 256, 0, stream>>>(emb, ebT_f32, ebfrag, enormp);
    vq_main<<<NROWS / 256, 256, 0, stream>>>(x, ebfrag, ebT_f32, enormp, out, loss_acc);
    vq_finalize<<<1, 64, 0, stream>>>(loss_acc, out + (size_t)TOTALF);
}

// Round 9
// 111.784 us; speedup vs baseline: 1.2172x; 1.0752x over previous
//
#include <hip/hip_runtime.h>
#include <stdint.h>

#define NROWS (512*256)          // 131072
#define DDIM 128
#define KCB 1024
#define TOTALF (NROWS*DDIM)      // 16777216
#define TAU 0.35f                // refine gate vs 2nd-best gap (r5-proven)
#define IDXMASK 0xFFFFFC00u      // clear low 10 mantissa bits for packed argmin keys

typedef __attribute__((ext_vector_type(8))) short short8v;
typedef __attribute__((ext_vector_type(4))) float f32x4;

static __device__ __forceinline__ unsigned short bf16_rne(float f) {
    unsigned u = __builtin_bit_cast(unsigned, f);
    u += 0x7FFFu + ((u >> 16) & 1u);
    return (unsigned short)(u >> 16);
}
static __device__ __forceinline__ float bf16_to_f32(unsigned short h) {
    unsigned u = ((unsigned)h) << 16;
    return __builtin_bit_cast(float, u);
}

// ---- prep: 64 blocks; block b handles cols [b*16, b*16+16).
// Blob layout (NEW): [ct 0..63][s 0..3][1024B], ct = global col-tile = blockIdx.
__global__ __launch_bounds__(256) void vq_prep(
    const float* __restrict__ emb,
    float* __restrict__ ebT_f32,
    char* __restrict__ ebfrag,
    float* __restrict__ enorm)
{
    __shared__ float T[128 * 17];
    __shared__ float red[256];
    const int t = threadIdx.x;
    const int k0 = blockIdx.x * 16;
    {
        const int c16 = t & 15;
        const int dq = t >> 4;
        #pragma unroll
        for (int i = 0; i < 8; ++i) {
            int d = dq * 8 + i;
            T[d * 17 + c16] = emb[(size_t)d * KCB + k0 + c16];
        }
    }
    __syncthreads();
    {
        const int c16 = t & 15, part = t >> 4;
        float s = 0.f;
        #pragma unroll
        for (int i = 0; i < 8; ++i) { float v = T[(part*8+i)*17 + c16]; s = fmaf(v, v, s); }
        red[part * 16 + c16] = s;
    }
    {
        const int col = t >> 4;
        const int d0 = (t & 15) * 8;
        f32x4 w0, w1;
        #pragma unroll
        for (int j = 0; j < 4; ++j) w0[j] = T[(d0 + j) * 17 + col];
        #pragma unroll
        for (int j = 0; j < 4; ++j) w1[j] = T[(d0 + 4 + j) * 17 + col];
        *(f32x4*)(ebT_f32 + (size_t)(k0 + col) * DDIM + d0) = w0;
        *(f32x4*)(ebT_f32 + (size_t)(k0 + col) * DDIM + d0 + 4) = w1;
    }
    {   // fragment-major bf16-hi blob, linear [ct][s][lane*16]
        const int s = t >> 6, l = t & 63;
        const int cc = l & 15, g = l >> 4;
        const int d0 = s * 32 + g * 8;
        short8v hv;
        #pragma unroll
        for (int j = 0; j < 8; ++j) hv[j] = (short)bf16_rne(T[(d0 + j) * 17 + cc]);
        *(short8v*)(ebfrag + (size_t)blockIdx.x * 4096 + s * 1024 + l * 16) = hv;
    }
    __syncthreads();
    if (t < 16) {
        float s = 0.f;
        #pragma unroll
        for (int p = 0; p < 16; ++p) s += red[p * 16 + t];
        enorm[k0 + t] = s;
    }
}

// async global->LDS, 16B per lane; lds_base wave-uniform, src per-lane
static __device__ __forceinline__ void gload_lds16(const char* src, char* lds_base) {
    __builtin_amdgcn_global_load_lds(
        (const __attribute__((address_space(1))) unsigned int*)src,
        (__attribute__((address_space(3))) unsigned int*)lds_base, 16, 0, 0);
}

// ---- main: B staged block-wide in LDS (2x32KB dbuf, 8 phases), r5 decision
//      logic unchanged (2-pass split-bf16, packed top-3, TAU=0.35 refine).
__global__ __launch_bounds__(256, 2) void vq_main(
    const float* __restrict__ x,
    const char* __restrict__ ebfrag,
    const float* __restrict__ ebT_f32,
    const float* __restrict__ enorm,
    float* __restrict__ out,
    float* __restrict__ loss_acc)
{
    __shared__ char lds[65536];                  // 2 x 32KB double buffer
    const int tid = threadIdx.x, wid = tid >> 6, lane = tid & 63;
    const int c = lane & 15, g = lane >> 4;
    const size_t wave_row = ((size_t)blockIdx.x * 4 + wid) * 64;

    // A fragments: 64 rows x 128 d, split hi/lo (layout r3/r5-proven)
    short8v a_hi[4][4], a_lo[4][4];
    float xsq = 0.f;
    #pragma unroll
    for (int m = 0; m < 4; ++m) {
      #pragma unroll
      for (int s = 0; s < 4; ++s) {
        const float* src = x + (wave_row + m * 16 + c) * DDIM + s * 32 + g * 8;
        f32x4 v0 = *(const f32x4*)src;
        f32x4 v1 = *(const f32x4*)(src + 4);
        #pragma unroll
        for (int j = 0; j < 8; ++j) {
            float f = (j < 4) ? v0[j] : v1[j - 4];
            unsigned short h = bf16_rne(f);
            float fh = bf16_to_f32(h);
            a_hi[m][s][j] = (short)h;
            a_lo[m][s][j] = (short)bf16_rne(f - fh);
            xsq = fmaf(f, f, xsq);
        }
      }
    }

    float tb[4][4], ts2[4][4], tt[4][4];
    #pragma unroll
    for (int m = 0; m < 4; ++m)
      #pragma unroll
      for (int r = 0; r < 4; ++r) { tb[m][r] = 3.4e38f; ts2[m][r] = 3.4e38f; tt[m][r] = 3.4e38f; }

    // stage phase 0: 32KB = 32 x 1KB segments; wave wid stages segs [wid*8, wid*8+8)
    {
        const char* src = ebfrag + (size_t)wid * 8192 + lane * 16;
        char* dst = lds + wid * 8192;
        #pragma unroll
        for (int i = 0; i < 8; ++i)
            gload_lds16(src + i * 1024, dst + i * 1024);
    }
    __syncthreads();

    for (int p = 0; p < 8; ++p) {
        const char* cur = lds + (p & 1) * 32768;
        if (p < 7) {   // stage next phase into the other buffer
            const char* src = ebfrag + (size_t)(p + 1) * 32768 + (size_t)wid * 8192 + lane * 16;
            char* dst = lds + ((p + 1) & 1) * 32768 + wid * 8192;
            #pragma unroll
            for (int i = 0; i < 8; ++i)
                gload_lds16(src + i * 1024, dst + i * 1024);
        }
        // compute 8 col-tiles from current buffer
        #pragma unroll 2
        for (int ctl = 0; ctl < 8; ++ctl) {
            short8v bh[4];
            #pragma unroll
            for (int s = 0; s < 4; ++s)
                bh[s] = *(const short8v*)(cur + ctl * 4096 + s * 1024 + lane * 16);
            const int colv = (p * 8 + ctl) * 16 + c;
            const float en = enorm[colv];
            f32x4 acc[4];
            #pragma unroll
            for (int m = 0; m < 4; ++m) acc[m] = (f32x4){0.f, 0.f, 0.f, 0.f};
            #pragma unroll
            for (int s = 0; s < 4; ++s) {
                #pragma unroll
                for (int m = 0; m < 4; ++m)
                    acc[m] = __builtin_amdgcn_mfma_f32_16x16x32_bf16(a_hi[m][s], bh[s], acc[m], 0, 0, 0);
                #pragma unroll
                for (int m = 0; m < 4; ++m)
                    acc[m] = __builtin_amdgcn_mfma_f32_16x16x32_bf16(a_lo[m][s], bh[s], acc[m], 0, 0, 0);
            }
            #pragma unroll
            for (int m = 0; m < 4; ++m)
              #pragma unroll
              for (int r = 0; r < 4; ++r) {
                float d = fmaf(-2.f, acc[m][r], en);      // ||x||^2 omitted
                unsigned db = __builtin_bit_cast(unsigned, d);
                float key = __builtin_bit_cast(float, (db & IDXMASK) | (unsigned)colv);
                tt[m][r]  = __builtin_amdgcn_fmed3f(key, ts2[m][r], tt[m][r]);  // new 3rd
                ts2[m][r] = __builtin_amdgcn_fmed3f(key, tb[m][r],  ts2[m][r]); // new 2nd
                tb[m][r]  = fminf(key, tb[m][r]);                                // new 1st
              }
        }
        __syncthreads();   // drains gload_lds (vmcnt0) + compute of this phase
    }

    // cross-lane top-3 merge over the 16 c-lanes (disjoint col sets)
    #pragma unroll
    for (int m = 0; m < 4; ++m)
      #pragma unroll
      for (int r = 0; r < 4; ++r) {
        float b = tb[m][r], s = ts2[m][r], t3 = tt[m][r];
        #pragma unroll
        for (int off = 1; off < 16; off <<= 1) {
            float ob = __shfl_xor(b, off, 64);
            float os = __shfl_xor(s, off, 64);
            float ot = __shfl_xor(t3, off, 64);
            t3 = __builtin_amdgcn_fmed3f(ob, s, t3);
            s  = __builtin_amdgcn_fmed3f(ob, b, s);
            b  = fminf(b, ob);
            t3 = __builtin_amdgcn_fmed3f(os, s, t3);
            s  = fminf(s, os);
            t3 = fminf(t3, ot);
        }
        tb[m][r] = b; ts2[m][r] = s; tt[m][r] = t3;
      }

    // refine: exact fp32 over top-3 where the 2nd-best gap is small
    float lsum = 0.f;
    #pragma unroll
    for (int m = 0; m < 4; ++m)
      #pragma unroll
      for (int r = 0; r < 4; ++r) {
        unsigned b1 = __builtin_bit_cast(unsigned, tb[m][r]);
        unsigned b2 = __builtin_bit_cast(unsigned, ts2[m][r]);
        int chosen = (int)(b1 & 1023u);
        float dch = __builtin_bit_cast(float, b1 & IDXMASK);
        float d2a = __builtin_bit_cast(float, b2 & IDXMASK);
        const size_t row = wave_row + m * 16 + g * 4 + r;
        if (d2a - dch < TAU) {      // uniform within 16-lane group
            unsigned b3 = __builtin_bit_cast(unsigned, tt[m][r]);
            int i1 = chosen, i2 = (int)(b2 & 1023u), i3 = (int)(b3 & 1023u);
            const f32x4* xp = (const f32x4*)(x + row * DDIM + c * 8);
            f32x4 x0 = xp[0], x1 = xp[1];
            const f32x4* e1 = (const f32x4*)(ebT_f32 + (size_t)i1 * DDIM + c * 8);
            const f32x4* e2 = (const f32x4*)(ebT_f32 + (size_t)i2 * DDIM + c * 8);
            const f32x4* e3 = (const f32x4*)(ebT_f32 + (size_t)i3 * DDIM + c * 8);
            f32x4 p10 = e1[0], p11 = e1[1];
            f32x4 p20 = e2[0], p21 = e2[1];
            f32x4 p30 = e3[0], p31 = e3[1];
            float q1 = 0.f, q2 = 0.f, q3 = 0.f;
            #pragma unroll
            for (int j = 0; j < 4; ++j) {
                q1 = fmaf(x0[j], p10[j], q1); q1 = fmaf(x1[j], p11[j], q1);
                q2 = fmaf(x0[j], p20[j], q2); q2 = fmaf(x1[j], p21[j], q2);
                q3 = fmaf(x0[j], p30[j], q3); q3 = fmaf(x1[j], p31[j], q3);
            }
            #pragma unroll
            for (int off = 1; off < 16; off <<= 1) {
                q1 += __shfl_xor(q1, off, 64);
                q2 += __shfl_xor(q2, off, 64);
                q3 += __shfl_xor(q3, off, 64);
            }
            float D1 = fmaf(-2.f, q1, enorm[i1]);
            float D2 = fmaf(-2.f, q2, enorm[i2]);
            float D3 = fmaf(-2.f, q3, enorm[i3]);
            float bd = D1; int bi = i1;
            if (D2 < bd || (D2 == bd && i2 < bi)) { bd = D2; bi = i2; }
            if (D3 < bd || (D3 == bd && i3 < bi)) { bd = D3; bi = i3; }
            chosen = bi; dch = bd;
        }
        const f32x4* qsrc = (const f32x4*)(ebT_f32 + (size_t)chosen * DDIM + c * 8);
        f32x4* dst = (f32x4*)(out + row * DDIM + c * 8);
        dst[0] = qsrc[0];
        dst[1] = qsrc[1];
        if (c == 0) lsum += dch;
      }

    // loss: sum(||x||^2) + sum(best_dist) == sum((q-x)^2)
    float part = xsq + lsum;
    #pragma unroll
    for (int off = 32; off > 0; off >>= 1) part += __shfl_down(part, off, 64);
    if (lane == 0) atomicAdd(loss_acc, part);
}

__global__ void vq_finalize(const float* __restrict__ loss_acc,
                            float* __restrict__ outl) {
    if (threadIdx.x == 0) {
        float l = loss_acc[0] * (1.0f / (float)TOTALF);
        outl[0] = l;           // codebook_loss
        outl[1] = 0.25f * l;   // commitment_loss = BETA * same value
    }
}

// ws layout: [0,512K) ebT_f32 | [512K,768K) ebfrag (linear [ct][s][1KB])
//            [768K,772K) enorm | [772K] loss_acc
extern "C" void kernel_launch(void* const* d_in, const int* in_sizes, int n_in,
                              void* d_out, int out_size, void* d_ws, size_t ws_size,
                              hipStream_t stream) {
    const float* x   = (const float*)d_in[0];
    const float* emb = (const float*)d_in[1];
    float* out = (float*)d_out;
    char* ws = (char*)d_ws;
    float* ebT_f32  = (float*)ws;
    char*  ebfrag   = ws + 512 * 1024;
    float* enormp   = (float*)(ws + 768 * 1024);
    float* loss_acc = (float*)(ws + 772 * 1024);

    hipMemsetAsync(loss_acc, 0, sizeof(float), stream);
    vq_prep<<<64, 256, 0, stream>>>(emb, ebT_f32, ebfrag, enormp);
    vq_main<<<NROWS / 256, 256, 0, stream>>>(x, ebfrag, ebT_f32, enormp, out, loss_acc);
    vq_finalize<<<1, 64, 0, stream>>>(loss_acc, out + (size_t)TOTALF);
}